// Round 7
// baseline (932.965 us; speedup 1.0000x reference)
//
#include <hip/hip_runtime.h>

// CIN fused 3-layer, bf16 MFMA, SINGLE-kernel (R7).
// cur[sl,n] = sum_f x_f[sl] * S_f[sl,n],  S_f = sum_g h_g[sl] * W[f*64+g, n].
// Changes vs R6:
//  - no prep kernel: W loaded as fp32 (8 dword loads per frag, literal imm
//    offsets), packed to bf16 in-register with v_perm (truncation).
//  - deferred x-apply: the VALU fold cur += x_f * S_f consumes the PREVIOUS
//    iteration's MFMA result (pv/xp rotation in named scalars) -> no
//    MFMA->VALU stall; MFMAs issued as 4 independent 2-chains.
//  - depth-2 B prefetch in named f32x8 scalars (SSA-safe, no scratch).

#define NF     39
#define LCH    128
#define NLAYER 3

typedef __bf16        bf16x8 __attribute__((ext_vector_type(8)));
typedef unsigned int  uint4v __attribute__((ext_vector_type(4)));
typedef float         f32x4  __attribute__((ext_vector_type(4)));
typedef float         f32x8  __attribute__((ext_vector_type(8)));

__device__ __forceinline__ unsigned short f2bf_rne(float f) {
    unsigned u = __float_as_uint(f);
    u += 0x7fffu + ((u >> 16) & 1u);
    return (unsigned short)(u >> 16);
}

// pack 8 fp32 -> bf16x8 by truncation: (hi & 0xffff0000) | (lo >> 16), 4 v_perm
#define PACKBF(SRC) __builtin_bit_cast(bf16x8, (uint4v){                                            \
    __builtin_amdgcn_perm(__float_as_uint((SRC)[1]), __float_as_uint((SRC)[0]), 0x07060302u),        \
    __builtin_amdgcn_perm(__float_as_uint((SRC)[3]), __float_as_uint((SRC)[2]), 0x07060302u),        \
    __builtin_amdgcn_perm(__float_as_uint((SRC)[5]), __float_as_uint((SRC)[4]), 0x07060302u),        \
    __builtin_amdgcn_perm(__float_as_uint((SRC)[7]), __float_as_uint((SRC)[6]), 0x07060302u)})

// Issue B-frag fp32 loads for tile (PL, PF) into D0 (ks=0) / D1 (ks=1).
// Lane (q,c) of wave w needs W[k = ks*32 + q*8 + j][nc], j=0..7.
// l==0 rows are (f*39+g)*128 with g<39: ks=0 all valid (g<=31); ks=1 only
// q==0, j<=6 valid (g=32..38; max addr = exactly last element of W0).
#define ISSUE_LOADS(PL, PF, D0, D1)                                            \
  do { if ((PL) < NLAYER) {                                                    \
    const float* _base = ((PL) == 0) ? (W0 + (PF) * 4992)                      \
                       : ((PL) == 1) ? (W1 + (PF) * 8192)                      \
                                     : (W2 + (PF) * 8192);                     \
    const float* _p0 = _base + lane_off;                                       \
    D0[0] = _p0[0];   D0[1] = _p0[128]; D0[2] = _p0[256]; D0[3] = _p0[384];    \
    D0[4] = _p0[512]; D0[5] = _p0[640]; D0[6] = _p0[768]; D0[7] = _p0[896];    \
    if ((PL) == 0) {                                                           \
      if (q == 0) {                                                            \
        const float* _p1 = _base + 4096 + nc;                                  \
        D1[0] = _p1[0];   D1[1] = _p1[128]; D1[2] = _p1[256];                  \
        D1[3] = _p1[384]; D1[4] = _p1[512]; D1[5] = _p1[640];                  \
        D1[6] = _p1[768]; D1[7] = 0.f;                                         \
      } else { D1 = (f32x8){0,0,0,0,0,0,0,0}; }                                \
    } else {                                                                   \
      const float* _p1 = _p0 + 4096;                                           \
      D1[0] = _p1[0];   D1[1] = _p1[128]; D1[2] = _p1[256]; D1[3] = _p1[384];  \
      D1[4] = _p1[512]; D1[5] = _p1[640]; D1[6] = _p1[768]; D1[7] = _p1[896];  \
    }                                                                          \
  } } while (0)

__global__ __launch_bounds__(512, 2) void cin_mfma(
    const float* __restrict__ x,
    const float* __restrict__ W0,
    const float* __restrict__ W1,
    const float* __restrict__ W2,
    const float* __restrict__ b0p,
    const float* __restrict__ b1p,
    const float* __restrict__ b2p,
    float* __restrict__ out)
{
    __shared__ __align__(16) unsigned short hfrag[8 * 64 * 8];  // [gblk][sl][j], 8 KB
    __shared__ float xf32[NF * 64];                             // [f][sl] fp32

    const int tid  = threadIdx.x;
    const int lane = tid & 63;
    const int w    = tid >> 6;      // wave 0..7 = n-tile
    const int q    = lane >> 4;     // quad 0..3
    const int c    = lane & 15;
    const int nc   = w * 16 + c;    // this lane's output channel
    const int bb   = blockIdx.x * 4;
    const int lane_off = q * 1024 + nc;   // q*8 rows * 128 + col

    // zero hfrag (covers layer-0 A-side padding g in [39,64))
    {
        f32x4 zz = {0.f, 0.f, 0.f, 0.f};
        ((f32x4*)hfrag)[tid] = zz;   // 512*16B = 8 KB exactly
    }
    __syncthreads();

    // stage x (contiguous 2496 floats for this block's 4 b's)
    for (int i = tid; i < 4 * NF * 16; i += 512) {
        const float v = x[bb * (NF * 16) + i];
        const int lb = i / (NF * 16);
        const int r  = i - lb * (NF * 16);
        const int f  = r >> 4;
        const int d  = r & 15;
        const int sl = lb * 16 + d;
        xf32[f * 64 + sl] = v;
        hfrag[((f >> 3) * 64 + sl) * 8 + (f & 7)] = f2bf_rne(v);
    }

    // per-lane biases (tiny, cached)
    const float biasv0 = b0p[nc];
    const float biasv1 = b1p[nc];
    const float biasv2 = b2p[nc];

    // prime depth-2 B prefetch (tiles 0 and 1, layer 0)
    f32x8 craw0, craw1, nraw0, nraw1;
    ISSUE_LOADS(0, 0, craw0, craw1);
    ISSUE_LOADS(0, 1, nraw0, nraw1);
    int pl = 0, pf = 2;   // next tile to prefetch

    __syncthreads();   // x, hfrag ready

    const f32x4 z = {0.f, 0.f, 0.f, 0.f};

    #pragma unroll 1
    for (int l = 0; l < NLAYER; ++l) {
        // hoist A-frags (h) for this layer: a<ks><mt>, named scalars
        const bf16x8 a00 = *(const bf16x8*)&hfrag[((0 + q) * 64 +  0 + c) * 8];
        const bf16x8 a01 = *(const bf16x8*)&hfrag[((0 + q) * 64 + 16 + c) * 8];
        const bf16x8 a02 = *(const bf16x8*)&hfrag[((0 + q) * 64 + 32 + c) * 8];
        const bf16x8 a03 = *(const bf16x8*)&hfrag[((0 + q) * 64 + 48 + c) * 8];
        const bf16x8 a10 = *(const bf16x8*)&hfrag[((4 + q) * 64 +  0 + c) * 8];
        const bf16x8 a11 = *(const bf16x8*)&hfrag[((4 + q) * 64 + 16 + c) * 8];
        const bf16x8 a12 = *(const bf16x8*)&hfrag[((4 + q) * 64 + 32 + c) * 8];
        const bf16x8 a13 = *(const bf16x8*)&hfrag[((4 + q) * 64 + 48 + c) * 8];

        f32x4 cur0 = z, cur1 = z, cur2 = z, cur3 = z;
        f32x4 pv0 = z, pv1 = z, pv2 = z, pv3 = z;      // previous S_f (retired)
        f32x4 xp0 = z, xp1 = z, xp2 = z, xp3 = z;      // previous x rows

        #pragma unroll 2
        for (int f = 0; f < NF; ++f) {
            // pack current tile's B-frags (loaded 2 iters ago)
            const bf16x8 bv0 = PACKBF(craw0);
            const bf16x8 bv1 = PACKBF(craw1);

            // 4 independent 2-chains: S_f for each m-tile
            f32x4 s0 = __builtin_amdgcn_mfma_f32_16x16x32_bf16(a00, bv0, z, 0, 0, 0);
            f32x4 s1 = __builtin_amdgcn_mfma_f32_16x16x32_bf16(a01, bv0, z, 0, 0, 0);
            f32x4 s2 = __builtin_amdgcn_mfma_f32_16x16x32_bf16(a02, bv0, z, 0, 0, 0);
            f32x4 s3 = __builtin_amdgcn_mfma_f32_16x16x32_bf16(a03, bv0, z, 0, 0, 0);
            s0 = __builtin_amdgcn_mfma_f32_16x16x32_bf16(a10, bv1, s0, 0, 0, 0);
            s1 = __builtin_amdgcn_mfma_f32_16x16x32_bf16(a11, bv1, s1, 0, 0, 0);
            s2 = __builtin_amdgcn_mfma_f32_16x16x32_bf16(a12, bv1, s2, 0, 0, 0);
            s3 = __builtin_amdgcn_mfma_f32_16x16x32_bf16(a13, bv1, s3, 0, 0, 0);

            // apply PREVIOUS iteration's S (fully retired -> no MFMA stall)
            #pragma unroll
            for (int r = 0; r < 4; ++r) {
                cur0[r] = fmaf(xp0[r], pv0[r], cur0[r]);
                cur1[r] = fmaf(xp1[r], pv1[r], cur1[r]);
                cur2[r] = fmaf(xp2[r], pv2[r], cur2[r]);
                cur3[r] = fmaf(xp3[r], pv3[r], cur3[r]);
            }

            // this tile's x rows (consumed next iter; LDS broadcast)
            const f32x4 xr0 = *(const f32x4*)&xf32[f * 64 +  0 + q * 4];
            const f32x4 xr1 = *(const f32x4*)&xf32[f * 64 + 16 + q * 4];
            const f32x4 xr2 = *(const f32x4*)&xf32[f * 64 + 32 + q * 4];
            const f32x4 xr3 = *(const f32x4*)&xf32[f * 64 + 48 + q * 4];

            // rotate pipeline state (SSA renames, no scratch)
            pv0 = s0; pv1 = s1; pv2 = s2; pv3 = s3;
            xp0 = xr0; xp1 = xr1; xp2 = xr2; xp3 = xr3;
            craw0 = nraw0; craw1 = nraw1;

            // prefetch tile tl+2
            ISSUE_LOADS(pl, pf, nraw0, nraw1);
            if (++pf == NF) { pf = 0; ++pl; }
        }

        // drain: apply last tile's S
        #pragma unroll
        for (int r = 0; r < 4; ++r) {
            cur0[r] = fmaf(xp0[r], pv0[r], cur0[r]);
            cur1[r] = fmaf(xp1[r], pv1[r], cur1[r]);
            cur2[r] = fmaf(xp2[r], pv2[r], cur2[r]);
            cur3[r] = fmaf(xp3[r], pv3[r], cur3[r]);
        }

        // ---------------- epilogue for layer l ----------------
        const float bias = (l == 0) ? biasv0 : (l == 1) ? biasv1 : biasv2;
        f32x4 curA[4] = {cur0, cur1, cur2, cur3};
        float v[4][4];
        #pragma unroll
        for (int mt = 0; mt < 4; ++mt)
            #pragma unroll
            for (int r = 0; r < 4; ++r)
                v[mt][r] = fmaxf(curA[mt][r] + bias, 0.f);

        if (l < 2 && w < 4) {
            // h channels (nc < 64): write next layer's h (C row = q*4+r)
            #pragma unroll
            for (int mt = 0; mt < 4; ++mt)
                #pragma unroll
                for (int r = 0; r < 4; ++r)
                    hfrag[((nc >> 3) * 64 + mt * 16 + q * 4 + r) * 8 + (nc & 7)] =
                        f2bf_rne(v[mt][r]);
        } else {
            // direct channels: reduce over d (= q*4+r) and store
            // l==0: nc 64..127 -> out 0..63 ; l==1: nc 64..127 -> out 64..127 ;
            // l==2: nc 0..127 -> out 128..255
            const int outcol = (l == 0) ? nc - 64 : (l == 1) ? nc : 128 + nc;
            #pragma unroll
            for (int mt = 0; mt < 4; ++mt) {
                float sacc = v[mt][0] + v[mt][1] + v[mt][2] + v[mt][3];
                sacc += __shfl_xor(sacc, 16, 64);
                sacc += __shfl_xor(sacc, 32, 64);
                if (lane < 16) out[(bb + mt) * 256 + outcol] = sacc;
            }
        }
        if (l < 2) __syncthreads();   // h writes visible before next A-hoist
    }
}

extern "C" void kernel_launch(void* const* d_in, const int* in_sizes, int n_in,
                              void* d_out, int out_size, void* d_ws, size_t ws_size,
                              hipStream_t stream) {
    const float* x  = (const float*)d_in[0];
    const float* W0 = (const float*)d_in[1];
    const float* W1 = (const float*)d_in[2];
    const float* W2 = (const float*)d_in[3];
    const float* b0 = (const float*)d_in[4];
    const float* b1 = (const float*)d_in[5];
    const float* b2 = (const float*)d_in[6];
    float* out = (float*)d_out;

    cin_mfma<<<256, 512, 0, stream>>>(x, W0, W1, W2, b0, b1, b2, out);
}

// Round 8
// 915.923 us; speedup vs baseline: 1.0186x; 1.0186x over previous
//
#include <hip/hip_runtime.h>

// CIN fused 3-layer, bf16 MFMA, SINGLE-kernel (R8 = R7 + VGPR-cap fix + slimmer state).
// cur[sl,n] = sum_f x_f[sl] * S_f[sl,n],  S_f = sum_g h_g[sl] * W[f*64+g, n].
// R4/R5/R7 lesson: __launch_bounds__ 2nd arg behaves like CUDA min-blocks/CU:
// (512,2) -> 4 waves/SIMD -> 128-VGPR cap -> spills (357MB..1.6GB scratch).
// R8: (512,1) -> 2 waves/SIMD -> 256-VGPR cap. Also: current W tile held as
// packed bf16 (8 regs, packed at rotation), deferred x-apply reads prev x
// from LDS (no xp registers). All pipeline state in named scalars (SSA-safe).

#define NF     39
#define LCH    128
#define NLAYER 3

typedef __bf16        bf16x8 __attribute__((ext_vector_type(8)));
typedef unsigned int  uint4v __attribute__((ext_vector_type(4)));
typedef float         f32x4  __attribute__((ext_vector_type(4)));
typedef float         f32x8  __attribute__((ext_vector_type(8)));

__device__ __forceinline__ unsigned short f2bf_rne(float f) {
    unsigned u = __float_as_uint(f);
    u += 0x7fffu + ((u >> 16) & 1u);
    return (unsigned short)(u >> 16);
}

// pack 8 fp32 -> bf16x8 by truncation: 4x v_perm (verified R7: passed, absmax .375)
#define PACKBF(SRC) __builtin_bit_cast(bf16x8, (uint4v){                                             \
    __builtin_amdgcn_perm(__float_as_uint((SRC)[1]), __float_as_uint((SRC)[0]), 0x07060302u),        \
    __builtin_amdgcn_perm(__float_as_uint((SRC)[3]), __float_as_uint((SRC)[2]), 0x07060302u),        \
    __builtin_amdgcn_perm(__float_as_uint((SRC)[5]), __float_as_uint((SRC)[4]), 0x07060302u),        \
    __builtin_amdgcn_perm(__float_as_uint((SRC)[7]), __float_as_uint((SRC)[6]), 0x07060302u)})

// Issue B-frag fp32 loads for tile (PL, PF) into D0 (ks=0) / D1 (ks=1).
// Lane (q,c) of wave w needs W[k = ks*32 + q*8 + j][nc], j=0..7.
// l==0 rows are (f*39+g)*128 with g<39: ks=0 all valid (g<=31); ks=1 only
// q==0, j<=6 valid (g=32..38; max addr = exactly last element of W0).
#define ISSUE_LOADS(PL, PF, D0, D1)                                            \
  do { if ((PL) < NLAYER) {                                                    \
    const float* _base = ((PL) == 0) ? (W0 + (PF) * 4992)                      \
                       : ((PL) == 1) ? (W1 + (PF) * 8192)                      \
                                     : (W2 + (PF) * 8192);                     \
    const float* _p0 = _base + lane_off;                                       \
    D0[0] = _p0[0];   D0[1] = _p0[128]; D0[2] = _p0[256]; D0[3] = _p0[384];    \
    D0[4] = _p0[512]; D0[5] = _p0[640]; D0[6] = _p0[768]; D0[7] = _p0[896];    \
    if ((PL) == 0) {                                                           \
      if (q == 0) {                                                            \
        const float* _p1 = _base + 4096 + nc;                                  \
        D1[0] = _p1[0];   D1[1] = _p1[128]; D1[2] = _p1[256];                  \
        D1[3] = _p1[384]; D1[4] = _p1[512]; D1[5] = _p1[640];                  \
        D1[6] = _p1[768]; D1[7] = 0.f;                                         \
      } else { D1 = (f32x8){0,0,0,0,0,0,0,0}; }                                \
    } else {                                                                   \
      const float* _p1 = _p0 + 4096;                                           \
      D1[0] = _p1[0];   D1[1] = _p1[128]; D1[2] = _p1[256]; D1[3] = _p1[384];  \
      D1[4] = _p1[512]; D1[5] = _p1[640]; D1[6] = _p1[768]; D1[7] = _p1[896];  \
    }                                                                          \
  } } while (0)

__global__ __launch_bounds__(512, 1) void cin_mfma(
    const float* __restrict__ x,
    const float* __restrict__ W0,
    const float* __restrict__ W1,
    const float* __restrict__ W2,
    const float* __restrict__ b0p,
    const float* __restrict__ b1p,
    const float* __restrict__ b2p,
    float* __restrict__ out)
{
    __shared__ __align__(16) unsigned short hfrag[8 * 64 * 8];  // [gblk][sl][j], 8 KB
    __shared__ float xf32[NF * 64];                             // [f][sl] fp32

    const int tid  = threadIdx.x;
    const int lane = tid & 63;
    const int w    = tid >> 6;      // wave 0..7 = n-tile
    const int q    = lane >> 4;     // quad 0..3
    const int c    = lane & 15;
    const int nc   = w * 16 + c;    // this lane's output channel
    const int bb   = blockIdx.x * 4;
    const int lane_off = q * 1024 + nc;   // q*8 rows * 128 + col

    // zero hfrag (covers layer-0 A-side padding g in [39,64))
    {
        f32x4 zz = {0.f, 0.f, 0.f, 0.f};
        ((f32x4*)hfrag)[tid] = zz;   // 512*16B = 8 KB exactly
    }
    __syncthreads();

    // stage x (contiguous 2496 floats for this block's 4 b's)
    for (int i = tid; i < 4 * NF * 16; i += 512) {
        const float v = x[bb * (NF * 16) + i];
        const int lb = i / (NF * 16);
        const int r  = i - lb * (NF * 16);
        const int f  = r >> 4;
        const int d  = r & 15;
        const int sl = lb * 16 + d;
        xf32[f * 64 + sl] = v;
        hfrag[((f >> 3) * 64 + sl) * 8 + (f & 7)] = f2bf_rne(v);
    }

    // per-lane biases (tiny, cached)
    const float biasv0 = b0p[nc];
    const float biasv1 = b1p[nc];
    const float biasv2 = b2p[nc];

    // prime pipeline: tile 0 packed now, tile 1 in flight
    f32x8 nraw0, nraw1;
    bf16x8 cbv0, cbv1;
    {
        f32x8 t0, t1;
        ISSUE_LOADS(0, 0, t0, t1);
        cbv0 = PACKBF(t0);
        cbv1 = PACKBF(t1);
    }
    ISSUE_LOADS(0, 1, nraw0, nraw1);
    int pl = 0, pf = 2;   // next tile to prefetch

    __syncthreads();   // x, hfrag ready

    const f32x4 z = {0.f, 0.f, 0.f, 0.f};

    #pragma unroll 1
    for (int l = 0; l < NLAYER; ++l) {
        // hoist A-frags (h) for this layer: named scalars, literal offsets
        const bf16x8 a00 = *(const bf16x8*)&hfrag[((0 + q) * 64 +  0 + c) * 8];
        const bf16x8 a01 = *(const bf16x8*)&hfrag[((0 + q) * 64 + 16 + c) * 8];
        const bf16x8 a02 = *(const bf16x8*)&hfrag[((0 + q) * 64 + 32 + c) * 8];
        const bf16x8 a03 = *(const bf16x8*)&hfrag[((0 + q) * 64 + 48 + c) * 8];
        const bf16x8 a10 = *(const bf16x8*)&hfrag[((4 + q) * 64 +  0 + c) * 8];
        const bf16x8 a11 = *(const bf16x8*)&hfrag[((4 + q) * 64 + 16 + c) * 8];
        const bf16x8 a12 = *(const bf16x8*)&hfrag[((4 + q) * 64 + 32 + c) * 8];
        const bf16x8 a13 = *(const bf16x8*)&hfrag[((4 + q) * 64 + 48 + c) * 8];

        f32x4 cur0 = z, cur1 = z, cur2 = z, cur3 = z;
        f32x4 pv0 = z, pv1 = z, pv2 = z, pv3 = z;      // previous iteration's S_f

        #pragma unroll 2
        for (int f = 0; f < NF; ++f) {
            // 4 independent 2-chains: S_f for each m-tile (cbv = tile f)
            f32x4 s0 = __builtin_amdgcn_mfma_f32_16x16x32_bf16(a00, cbv0, z, 0, 0, 0);
            f32x4 s1 = __builtin_amdgcn_mfma_f32_16x16x32_bf16(a01, cbv0, z, 0, 0, 0);
            f32x4 s2 = __builtin_amdgcn_mfma_f32_16x16x32_bf16(a02, cbv0, z, 0, 0, 0);
            f32x4 s3 = __builtin_amdgcn_mfma_f32_16x16x32_bf16(a03, cbv0, z, 0, 0, 0);
            s0 = __builtin_amdgcn_mfma_f32_16x16x32_bf16(a10, cbv1, s0, 0, 0, 0);
            s1 = __builtin_amdgcn_mfma_f32_16x16x32_bf16(a11, cbv1, s1, 0, 0, 0);
            s2 = __builtin_amdgcn_mfma_f32_16x16x32_bf16(a12, cbv1, s2, 0, 0, 0);
            s3 = __builtin_amdgcn_mfma_f32_16x16x32_bf16(a13, cbv1, s3, 0, 0, 0);

            // apply PREVIOUS iteration's S (retired) with x rows read from LDS
            {
                const int fp = (f == 0) ? 0 : f - 1;   // pv==0 at f==0, value moot
                const f32x4 xr0 = *(const f32x4*)&xf32[fp * 64 +  0 + q * 4];
                const f32x4 xr1 = *(const f32x4*)&xf32[fp * 64 + 16 + q * 4];
                const f32x4 xr2 = *(const f32x4*)&xf32[fp * 64 + 32 + q * 4];
                const f32x4 xr3 = *(const f32x4*)&xf32[fp * 64 + 48 + q * 4];
                #pragma unroll
                for (int r = 0; r < 4; ++r) {
                    cur0[r] = fmaf(xr0[r], pv0[r], cur0[r]);
                    cur1[r] = fmaf(xr1[r], pv1[r], cur1[r]);
                    cur2[r] = fmaf(xr2[r], pv2[r], cur2[r]);
                    cur3[r] = fmaf(xr3[r], pv3[r], cur3[r]);
                }
            }

            // rotate: this iteration's S becomes next iteration's pv;
            // pack tile f+1 (loads issued last iter, ~1 iter in flight);
            // issue tile f+2 loads into nraw.
            pv0 = s0; pv1 = s1; pv2 = s2; pv3 = s3;
            cbv0 = PACKBF(nraw0);
            cbv1 = PACKBF(nraw1);
            ISSUE_LOADS(pl, pf, nraw0, nraw1);
            if (++pf == NF) { pf = 0; ++pl; }
        }

        // drain: apply last tile's S (x row f = NF-1)
        {
            const f32x4 xr0 = *(const f32x4*)&xf32[(NF - 1) * 64 +  0 + q * 4];
            const f32x4 xr1 = *(const f32x4*)&xf32[(NF - 1) * 64 + 16 + q * 4];
            const f32x4 xr2 = *(const f32x4*)&xf32[(NF - 1) * 64 + 32 + q * 4];
            const f32x4 xr3 = *(const f32x4*)&xf32[(NF - 1) * 64 + 48 + q * 4];
            #pragma unroll
            for (int r = 0; r < 4; ++r) {
                cur0[r] = fmaf(xr0[r], pv0[r], cur0[r]);
                cur1[r] = fmaf(xr1[r], pv1[r], cur1[r]);
                cur2[r] = fmaf(xr2[r], pv2[r], cur2[r]);
                cur3[r] = fmaf(xr3[r], pv3[r], cur3[r]);
            }
        }

        // ---------------- epilogue for layer l ----------------
        const float bias = (l == 0) ? biasv0 : (l == 1) ? biasv1 : biasv2;
        f32x4 curA[4] = {cur0, cur1, cur2, cur3};
        float v[4][4];
        #pragma unroll
        for (int mt = 0; mt < 4; ++mt)
            #pragma unroll
            for (int r = 0; r < 4; ++r)
                v[mt][r] = fmaxf(curA[mt][r] + bias, 0.f);

        if (l < 2 && w < 4) {
            // h channels (nc < 64): write next layer's h (C row = q*4+r)
            #pragma unroll
            for (int mt = 0; mt < 4; ++mt)
                #pragma unroll
                for (int r = 0; r < 4; ++r)
                    hfrag[((nc >> 3) * 64 + mt * 16 + q * 4 + r) * 8 + (nc & 7)] =
                        f2bf_rne(v[mt][r]);
        } else {
            // direct channels: reduce over d (= q*4+r) and store
            // l==0: nc 64..127 -> out 0..63 ; l==1: nc 64..127 -> out 64..127 ;
            // l==2: nc 0..127 -> out 128..255
            const int outcol = (l == 0) ? nc - 64 : (l == 1) ? nc : 128 + nc;
            #pragma unroll
            for (int mt = 0; mt < 4; ++mt) {
                float sacc = v[mt][0] + v[mt][1] + v[mt][2] + v[mt][3];
                sacc += __shfl_xor(sacc, 16, 64);
                sacc += __shfl_xor(sacc, 32, 64);
                if (lane < 16) out[(bb + mt) * 256 + outcol] = sacc;
            }
        }
        if (l < 2) __syncthreads();   // h writes visible before next A-hoist
    }
}

extern "C" void kernel_launch(void* const* d_in, const int* in_sizes, int n_in,
                              void* d_out, int out_size, void* d_ws, size_t ws_size,
                              hipStream_t stream) {
    const float* x  = (const float*)d_in[0];
    const float* W0 = (const float*)d_in[1];
    const float* W1 = (const float*)d_in[2];
    const float* W2 = (const float*)d_in[3];
    const float* b0 = (const float*)d_in[4];
    const float* b1 = (const float*)d_in[5];
    const float* b2 = (const float*)d_in[6];
    float* out = (float*)d_out;

    cin_mfma<<<256, 512, 0, stream>>>(x, W0, W1, W2, b0, b1, b2, out);
}

// Round 9
// 138.339 us; speedup vs baseline: 6.7441x; 6.6209x over previous
//
#include <hip/hip_runtime.h>
#include <hip/hip_cooperative_groups.h>

namespace cg = cooperative_groups;

// CIN fused 3-layer, bf16 MFMA, cooperative SINGLE kernel (R9).
// cur[sl,n] = sum_f x_f[sl] * S_f[sl,n],  S_f = sum_g h_g[sl] * W[f*64+g, n].
// Phase 1 (grid-wide): W fp32 -> bf16 frag-ready tiles in d_ws (R3 layout):
//   wt[tl*8192 + ((ks*4+q)*128 + n)*8 + j] = bf16(W_l[f*64 + ks*32+q*8+j][n])
// grid.sync(), then phase 2: barrier-free f-loop; wave w owns n-tile w and all
// 4 m-tiles; B-frags streamed L2->VGPR as bf16 (8 regs/buffer), manual
// ping/pong with NAMED buffers + compile-time role swap (39 odd => roles
// alternate per layer) -> no rotate copies, no runtime-indexed arrays, depth-2.
// R4/5/7/8 lesson: VGPR alloc is pinned at 128 for 512-thr blocks on this
// toolchain; total demand here ~110 regs.

#define NF     39
#define LCH    128
#define NLAYER 3
#define NFT    117

typedef __bf16        bf16x8 __attribute__((ext_vector_type(8)));
typedef unsigned int  uint4v __attribute__((ext_vector_type(4)));
typedef float         f32x4  __attribute__((ext_vector_type(4)));

__device__ __forceinline__ unsigned short f2bf_rne(float f) {
    unsigned u = __float_as_uint(f);
    u += 0x7fffu + ((u >> 16) & 1u);
    return (unsigned short)(u >> 16);
}

__device__ __forceinline__ void mfma_step(
    const bf16x8 a00, const bf16x8 a01, const bf16x8 a02, const bf16x8 a03,
    const bf16x8 a10, const bf16x8 a11, const bf16x8 a12, const bf16x8 a13,
    const bf16x8 B0, const bf16x8 B1,
    f32x4& cur0, f32x4& cur1, f32x4& cur2, f32x4& cur3,
    const float* xrow, int q)
{
    const f32x4 z = {0.f, 0.f, 0.f, 0.f};
    f32x4 s0 = __builtin_amdgcn_mfma_f32_16x16x32_bf16(a00, B0, z, 0, 0, 0);
    f32x4 s1 = __builtin_amdgcn_mfma_f32_16x16x32_bf16(a01, B0, z, 0, 0, 0);
    f32x4 s2 = __builtin_amdgcn_mfma_f32_16x16x32_bf16(a02, B0, z, 0, 0, 0);
    f32x4 s3 = __builtin_amdgcn_mfma_f32_16x16x32_bf16(a03, B0, z, 0, 0, 0);
    s0 = __builtin_amdgcn_mfma_f32_16x16x32_bf16(a10, B1, s0, 0, 0, 0);
    s1 = __builtin_amdgcn_mfma_f32_16x16x32_bf16(a11, B1, s1, 0, 0, 0);
    s2 = __builtin_amdgcn_mfma_f32_16x16x32_bf16(a12, B1, s2, 0, 0, 0);
    s3 = __builtin_amdgcn_mfma_f32_16x16x32_bf16(a13, B1, s3, 0, 0, 0);
    const f32x4 xr0 = *(const f32x4*)&xrow[ 0 + q * 4];
    const f32x4 xr1 = *(const f32x4*)&xrow[16 + q * 4];
    const f32x4 xr2 = *(const f32x4*)&xrow[32 + q * 4];
    const f32x4 xr3 = *(const f32x4*)&xrow[48 + q * 4];
    #pragma unroll
    for (int r = 0; r < 4; ++r) {
        cur0[r] = fmaf(xr0[r], s0[r], cur0[r]);
        cur1[r] = fmaf(xr1[r], s1[r], cur1[r]);
        cur2[r] = fmaf(xr2[r], s2[r], cur2[r]);
        cur3[r] = fmaf(xr3[r], s3[r], cur3[r]);
    }
}

// load B-frags for tile TL into (B0,B1); clamped duplicate loads past the end
#define LOADB(B0, B1, TL)                                                     \
    { int _t = (TL); if (_t > NFT - 1) _t = NFT - 1;                          \
      const unsigned short* _p = wq + (size_t)_t * 8192;                      \
      B0 = *(const bf16x8*)_p; B1 = *(const bf16x8*)(_p + 4096); }

#define HSTORE(CUR, MT)                                                       \
    { hfrag[((nc >> 3) * 64 + (MT) * 16 + q * 4 + 0) * 8 + (nc & 7)] =        \
          f2bf_rne(fmaxf(CUR[0] + bias, 0.f));                                \
      hfrag[((nc >> 3) * 64 + (MT) * 16 + q * 4 + 1) * 8 + (nc & 7)] =        \
          f2bf_rne(fmaxf(CUR[1] + bias, 0.f));                                \
      hfrag[((nc >> 3) * 64 + (MT) * 16 + q * 4 + 2) * 8 + (nc & 7)] =        \
          f2bf_rne(fmaxf(CUR[2] + bias, 0.f));                                \
      hfrag[((nc >> 3) * 64 + (MT) * 16 + q * 4 + 3) * 8 + (nc & 7)] =        \
          f2bf_rne(fmaxf(CUR[3] + bias, 0.f)); }

#define DSTORE(CUR, MT)                                                       \
    { float sacc = fmaxf(CUR[0] + bias, 0.f) + fmaxf(CUR[1] + bias, 0.f)      \
                 + fmaxf(CUR[2] + bias, 0.f) + fmaxf(CUR[3] + bias, 0.f);     \
      sacc += __shfl_xor(sacc, 16, 64);                                       \
      sacc += __shfl_xor(sacc, 32, 64);                                       \
      if (lane < 16) out[(bb + (MT)) * 256 + outcol] = sacc; }

// One layer: FA/FB are the named ping/pong buffer pairs in consumption order.
// Entry invariant: FA = tile L*39, FB = tile L*39+1 (in regs).
// Exit: other-parity pair holds next layer's tile 0; FA pair holds tile 1.
#define LAYERBODY(L, FA0, FA1, FB0, FB1)                                      \
  { const bf16x8 a00 = *(const bf16x8*)&hfrag[((0 + q) * 64 +  0 + c) * 8];   \
    const bf16x8 a01 = *(const bf16x8*)&hfrag[((0 + q) * 64 + 16 + c) * 8];   \
    const bf16x8 a02 = *(const bf16x8*)&hfrag[((0 + q) * 64 + 32 + c) * 8];   \
    const bf16x8 a03 = *(const bf16x8*)&hfrag[((0 + q) * 64 + 48 + c) * 8];   \
    const bf16x8 a10 = *(const bf16x8*)&hfrag[((4 + q) * 64 +  0 + c) * 8];   \
    const bf16x8 a11 = *(const bf16x8*)&hfrag[((4 + q) * 64 + 16 + c) * 8];   \
    const bf16x8 a12 = *(const bf16x8*)&hfrag[((4 + q) * 64 + 32 + c) * 8];   \
    const bf16x8 a13 = *(const bf16x8*)&hfrag[((4 + q) * 64 + 48 + c) * 8];   \
    f32x4 cur0 = {0,0,0,0}, cur1 = {0,0,0,0};                                 \
    f32x4 cur2 = {0,0,0,0}, cur3 = {0,0,0,0};                                 \
    int f = 0;                                                                \
    _Pragma("unroll 1")                                                       \
    for (int it = 0; it < 19; ++it) {                                         \
        mfma_step(a00,a01,a02,a03,a10,a11,a12,a13, FA0, FA1,                  \
                  cur0,cur1,cur2,cur3, &xf32[f * 64], q);                     \
        LOADB(FA0, FA1, (L) * NF + f + 2);                                    \
        mfma_step(a00,a01,a02,a03,a10,a11,a12,a13, FB0, FB1,                  \
                  cur0,cur1,cur2,cur3, &xf32[(f + 1) * 64], q);               \
        LOADB(FB0, FB1, (L) * NF + f + 3);                                    \
        f += 2;                                                               \
    }                                                                         \
    mfma_step(a00,a01,a02,a03,a10,a11,a12,a13, FA0, FA1,                      \
              cur0,cur1,cur2,cur3, &xf32[38 * 64], q);                        \
    LOADB(FA0, FA1, (L) * NF + 40);                                           \
    const float bias = ((L) == 0) ? biasv0 : ((L) == 1) ? biasv1 : biasv2;    \
    if ((L) < 2 && w < 4) {                                                   \
        HSTORE(cur0, 0) HSTORE(cur1, 1) HSTORE(cur2, 2) HSTORE(cur3, 3)       \
    } else {                                                                  \
        const int outcol = ((L) == 0) ? nc - 64 : ((L) == 1) ? nc : 128 + nc; \
        DSTORE(cur0, 0) DSTORE(cur1, 1) DSTORE(cur2, 2) DSTORE(cur3, 3)       \
    }                                                                         \
    if ((L) < 2) __syncthreads(); }

__global__ __launch_bounds__(512, 1) void cin_all(
    const float* __restrict__ x,
    const float* __restrict__ W0,
    const float* __restrict__ W1,
    const float* __restrict__ W2,
    unsigned short* __restrict__ wt,
    const float* __restrict__ b0p,
    const float* __restrict__ b1p,
    const float* __restrict__ b2p,
    float* __restrict__ out)
{
    __shared__ __align__(16) unsigned short hfrag[8 * 64 * 8];  // [gblk][sl][j], 8 KB
    __shared__ float xf32[NF * 64];                             // [f][sl] fp32

    const int tid  = threadIdx.x;
    const int lane = tid & 63;
    const int w    = tid >> 6;      // wave 0..7 = n-tile
    const int q    = lane >> 4;     // quad 0..3
    const int c    = lane & 15;
    const int nc   = w * 16 + c;    // this lane's output channel
    const int bb   = blockIdx.x * 4;

    // ---------- phase 1: W -> bf16 frag tiles (grid-wide, 1 chunk/thread) ----
    {
        const int t = blockIdx.x * 512 + tid;   // ((tl*2+ks)*4+qq)*128 + n
        if (t < NFT * 1024) {
            const int n  = t & 127;
            const int qq = (t >> 7) & 3;
            const int ks = (t >> 9) & 1;
            const int tl = t >> 10;
            const int l  = tl / NF;
            const int f  = tl - l * NF;
            const float* W = (l == 0) ? W0 : (l == 1) ? W1 : W2;
            unsigned short v[8];
            #pragma unroll
            for (int j = 0; j < 8; ++j) {
                const int g = ks * 32 + qq * 8 + j;
                float wv = 0.0f;
                if (l == 0) { if (g < NF) wv = W[(f * NF + g) * LCH + n]; }
                else        { wv = W[(f * 64 + g) * LCH + n]; }
                v[j] = f2bf_rne(wv);
            }
            uint4v pv;
            #pragma unroll
            for (int i = 0; i < 4; ++i)
                pv[i] = (unsigned)v[2 * i] | ((unsigned)v[2 * i + 1] << 16);
            ((uint4v*)wt)[t] = pv;   // 16B coalesced
        }
    }

    // ---------- block-local staging (independent of wt) ----------
    {
        f32x4 zz = {0.f, 0.f, 0.f, 0.f};
        ((f32x4*)hfrag)[tid] = zz;   // zero (covers layer-0 padding g in [39,64))
    }
    __syncthreads();
    for (int i = tid; i < 4 * NF * 16; i += 512) {
        const float v = x[bb * (NF * 16) + i];
        const int lb = i / (NF * 16);
        const int r  = i - lb * (NF * 16);
        const int f  = r >> 4;
        const int d  = r & 15;
        const int sl = lb * 16 + d;
        xf32[f * 64 + sl] = v;
        hfrag[((f >> 3) * 64 + sl) * 8 + (f & 7)] = f2bf_rne(v);
    }
    const float biasv0 = b0p[nc];
    const float biasv1 = b1p[nc];
    const float biasv2 = b2p[nc];

    // ---------- grid-wide sync: wt fully written & visible ----------
    cg::this_grid().sync();

    // per-lane base into wt frag layout: ks=0 at +0, ks=1 at +4096 shorts
    const unsigned short* wq = wt + (q * 128 + nc) * 8;

    // preload tiles 0 and 1 into the two named buffer pairs
    bf16x8 F0, F1, S0, S1;
    LOADB(F0, F1, 0);
    LOADB(S0, S1, 1);

    // layers; buffer roles alternate because 39 is odd
    LAYERBODY(0, F0, F1, S0, S1)
    LAYERBODY(1, S0, S1, F0, F1)
    LAYERBODY(2, F0, F1, S0, S1)
}

extern "C" void kernel_launch(void* const* d_in, const int* in_sizes, int n_in,
                              void* d_out, int out_size, void* d_ws, size_t ws_size,
                              hipStream_t stream) {
    const float* x  = (const float*)d_in[0];
    const float* W0 = (const float*)d_in[1];
    const float* W1 = (const float*)d_in[2];
    const float* W2 = (const float*)d_in[3];
    const float* b0 = (const float*)d_in[4];
    const float* b1 = (const float*)d_in[5];
    const float* b2 = (const float*)d_in[6];
    float* out = (float*)d_out;
    unsigned short* wt = (unsigned short*)d_ws;  // 117*8192*2 B = 1.87 MB

    void* args[] = { (void*)&x, (void*)&W0, (void*)&W1, (void*)&W2,
                     (void*)&wt, (void*)&b0, (void*)&b1, (void*)&b2, (void*)&out };
    hipLaunchCooperativeKernel((const void*)cin_all, dim3(256), dim3(512),
                               args, 0, stream);
}

// Round 10
// 120.213 us; speedup vs baseline: 7.7609x; 1.1508x over previous
//
#include <hip/hip_runtime.h>

// CIN fused 3-layer, bf16 MFMA, plain SINGLE kernel, fp32 W streaming (R10).
// cur[sl,n] = sum_f x_f[sl] * S_f[sl,n],  S_f = sum_g h_g[sl] * W[f*64+g, n].
// Wave w (0..7) owns n-tile w and all 4 m-tiles. W is read as fp32 straight
// from the input tensors (no prep kernel, no d_ws, no coop — R9 showed coop
// launch costs ~80us residual vs ~31-48 for a plain single kernel).
// B staging: two named fp32 tile-pairs (EA/EB), ping/pong via compile-time
// role swap per layer (39 odd) — R9's spill-free skeleton. Pack fp32->bf16
// (truncation, validated R7/R8) at consume with v_perm. 128-VGPR cap is
// immovable for 512-thr blocks (R4/5/7/8); demand here ~120.

#define NF     39
#define LCH    128
#define NLAYER 3

typedef __bf16        bf16x8 __attribute__((ext_vector_type(8)));
typedef unsigned int  uint4v __attribute__((ext_vector_type(4)));
typedef float         f32x4  __attribute__((ext_vector_type(4)));
typedef float         f32x8  __attribute__((ext_vector_type(8)));

__device__ __forceinline__ unsigned short f2bf_rne(float f) {
    unsigned u = __float_as_uint(f);
    u += 0x7fffu + ((u >> 16) & 1u);
    return (unsigned short)(u >> 16);
}

// pack 8 fp32 -> bf16x8 by truncation (4x v_perm)
#define PACKBF(SRC) __builtin_bit_cast(bf16x8, (uint4v){                                             \
    __builtin_amdgcn_perm(__float_as_uint((SRC)[1]), __float_as_uint((SRC)[0]), 0x07060302u),        \
    __builtin_amdgcn_perm(__float_as_uint((SRC)[3]), __float_as_uint((SRC)[2]), 0x07060302u),        \
    __builtin_amdgcn_perm(__float_as_uint((SRC)[5]), __float_as_uint((SRC)[4]), 0x07060302u),        \
    __builtin_amdgcn_perm(__float_as_uint((SRC)[7]), __float_as_uint((SRC)[6]), 0x07060302u)})

// fp32 B-frag loads for layer-relative tile (L, FO), FO may be in [0, NF+2]:
// normalize one layer crossing, skip entirely past the end (values unused).
// Lane (q,c) of wave w needs W[k = ks*32 + q*8 + j][nc], j=0..7.
// Layer-0 rows are (f*39+g)*128, g<39: ks=0 fully valid; ks=1 only q==0,j<=6.
#define LOADW(DA, DB, L, FO)                                                   \
  do { int _pl = (L), _pf = (FO);                                              \
    if (_pf >= NF) { _pf -= NF; ++_pl; }                                       \
    if (_pl < NLAYER) {                                                        \
      const float* _base = (_pl == 0) ? (W0 + _pf * 4992)                      \
                         : (_pl == 1) ? (W1 + _pf * 8192)                      \
                                      : (W2 + _pf * 8192);                     \
      const float* _p0 = _base + lane_off;                                     \
      DA[0] = _p0[0];   DA[1] = _p0[128]; DA[2] = _p0[256]; DA[3] = _p0[384];  \
      DA[4] = _p0[512]; DA[5] = _p0[640]; DA[6] = _p0[768]; DA[7] = _p0[896];  \
      if (_pl == 0) {                                                          \
        if (q == 0) {                                                          \
          const float* _p1 = _base + 4096 + nc;                                \
          DB[0] = _p1[0];   DB[1] = _p1[128]; DB[2] = _p1[256];                \
          DB[3] = _p1[384]; DB[4] = _p1[512]; DB[5] = _p1[640];                \
          DB[6] = _p1[768]; DB[7] = 0.f;                                       \
        } else { DB = (f32x8){0,0,0,0,0,0,0,0}; }                              \
      } else {                                                                 \
        const float* _p1 = _p0 + 4096;                                         \
        DB[0] = _p1[0];   DB[1] = _p1[128]; DB[2] = _p1[256]; DB[3] = _p1[384];\
        DB[4] = _p1[512]; DB[5] = _p1[640]; DB[6] = _p1[768]; DB[7] = _p1[896];\
      }                                                                        \
    }                                                                          \
  } while (0)

__device__ __forceinline__ void mfma_step(
    const bf16x8 a00, const bf16x8 a01, const bf16x8 a02, const bf16x8 a03,
    const bf16x8 a10, const bf16x8 a11, const bf16x8 a12, const bf16x8 a13,
    const f32x8& ra, const f32x8& rb,
    f32x4& cur0, f32x4& cur1, f32x4& cur2, f32x4& cur3,
    const float* xrow, int q)
{
    const bf16x8 B0 = PACKBF(ra);
    const bf16x8 B1 = PACKBF(rb);
    const f32x4 z = {0.f, 0.f, 0.f, 0.f};
    f32x4 s0 = __builtin_amdgcn_mfma_f32_16x16x32_bf16(a00, B0, z, 0, 0, 0);
    f32x4 s1 = __builtin_amdgcn_mfma_f32_16x16x32_bf16(a01, B0, z, 0, 0, 0);
    f32x4 s2 = __builtin_amdgcn_mfma_f32_16x16x32_bf16(a02, B0, z, 0, 0, 0);
    f32x4 s3 = __builtin_amdgcn_mfma_f32_16x16x32_bf16(a03, B0, z, 0, 0, 0);
    s0 = __builtin_amdgcn_mfma_f32_16x16x32_bf16(a10, B1, s0, 0, 0, 0);
    s1 = __builtin_amdgcn_mfma_f32_16x16x32_bf16(a11, B1, s1, 0, 0, 0);
    s2 = __builtin_amdgcn_mfma_f32_16x16x32_bf16(a12, B1, s2, 0, 0, 0);
    s3 = __builtin_amdgcn_mfma_f32_16x16x32_bf16(a13, B1, s3, 0, 0, 0);
    const f32x4 xr0 = *(const f32x4*)&xrow[ 0 + q * 4];
    const f32x4 xr1 = *(const f32x4*)&xrow[16 + q * 4];
    const f32x4 xr2 = *(const f32x4*)&xrow[32 + q * 4];
    const f32x4 xr3 = *(const f32x4*)&xrow[48 + q * 4];
    #pragma unroll
    for (int r = 0; r < 4; ++r) {
        cur0[r] = fmaf(xr0[r], s0[r], cur0[r]);
        cur1[r] = fmaf(xr1[r], s1[r], cur1[r]);
        cur2[r] = fmaf(xr2[r], s2[r], cur2[r]);
        cur3[r] = fmaf(xr3[r], s3[r], cur3[r]);
    }
}

#define HSTORE(CUR, MT)                                                       \
    { hfrag[((nc >> 3) * 64 + (MT) * 16 + q * 4 + 0) * 8 + (nc & 7)] =        \
          f2bf_rne(fmaxf(CUR[0] + bias, 0.f));                                \
      hfrag[((nc >> 3) * 64 + (MT) * 16 + q * 4 + 1) * 8 + (nc & 7)] =        \
          f2bf_rne(fmaxf(CUR[1] + bias, 0.f));                                \
      hfrag[((nc >> 3) * 64 + (MT) * 16 + q * 4 + 2) * 8 + (nc & 7)] =        \
          f2bf_rne(fmaxf(CUR[2] + bias, 0.f));                                \
      hfrag[((nc >> 3) * 64 + (MT) * 16 + q * 4 + 3) * 8 + (nc & 7)] =        \
          f2bf_rne(fmaxf(CUR[3] + bias, 0.f)); }

#define DSTORE(CUR, MT)                                                       \
    { float sacc = fmaxf(CUR[0] + bias, 0.f) + fmaxf(CUR[1] + bias, 0.f)      \
                 + fmaxf(CUR[2] + bias, 0.f) + fmaxf(CUR[3] + bias, 0.f);     \
      sacc += __shfl_xor(sacc, 16, 64);                                       \
      sacc += __shfl_xor(sacc, 32, 64);                                       \
      if (lane < 16) out[(bb + (MT)) * 256 + outcol] = sacc; }

// One layer. (FAa,FAb)/(FBa,FBb) = named fp32 ping/pong tile-pairs in
// consumption order. Entry: FA = tile (L,0), FB = tile (L,1), in regs.
// Exit: other-parity pair = tile (L+1,0); FA pair = tile (L+1,1).
#define LAYERBODY(L, FAa, FAb, FBa, FBb)                                      \
  { const bf16x8 a00 = *(const bf16x8*)&hfrag[((0 + q) * 64 +  0 + c) * 8];   \
    const bf16x8 a01 = *(const bf16x8*)&hfrag[((0 + q) * 64 + 16 + c) * 8];   \
    const bf16x8 a02 = *(const bf16x8*)&hfrag[((0 + q) * 64 + 32 + c) * 8];   \
    const bf16x8 a03 = *(const bf16x8*)&hfrag[((0 + q) * 64 + 48 + c) * 8];   \
    const bf16x8 a10 = *(const bf16x8*)&hfrag[((4 + q) * 64 +  0 + c) * 8];   \
    const bf16x8 a11 = *(const bf16x8*)&hfrag[((4 + q) * 64 + 16 + c) * 8];   \
    const bf16x8 a12 = *(const bf16x8*)&hfrag[((4 + q) * 64 + 32 + c) * 8];   \
    const bf16x8 a13 = *(const bf16x8*)&hfrag[((4 + q) * 64 + 48 + c) * 8];   \
    f32x4 cur0 = {0,0,0,0}, cur1 = {0,0,0,0};                                 \
    f32x4 cur2 = {0,0,0,0}, cur3 = {0,0,0,0};                                 \
    int f = 0;                                                                \
    _Pragma("unroll 1")                                                       \
    for (int it = 0; it < 19; ++it) {                                         \
        mfma_step(a00,a01,a02,a03,a10,a11,a12,a13, FAa, FAb,                  \
                  cur0,cur1,cur2,cur3, &xf32[f * 64], q);                     \
        LOADW(FAa, FAb, (L), f + 2);                                          \
        mfma_step(a00,a01,a02,a03,a10,a11,a12,a13, FBa, FBb,                  \
                  cur0,cur1,cur2,cur3, &xf32[(f + 1) * 64], q);               \
        LOADW(FBa, FBb, (L), f + 3);                                          \
        f += 2;                                                               \
    }                                                                         \
    mfma_step(a00,a01,a02,a03,a10,a11,a12,a13, FAa, FAb,                      \
              cur0,cur1,cur2,cur3, &xf32[38 * 64], q);                        \
    LOADW(FAa, FAb, (L), 40);                                                 \
    const float bias = ((L) == 0) ? biasv0 : ((L) == 1) ? biasv1 : biasv2;    \
    if ((L) < 2 && w < 4) {                                                   \
        HSTORE(cur0, 0) HSTORE(cur1, 1) HSTORE(cur2, 2) HSTORE(cur3, 3)       \
    } else {                                                                  \
        const int outcol = ((L) == 0) ? nc - 64 : ((L) == 1) ? nc : 128 + nc; \
        DSTORE(cur0, 0) DSTORE(cur1, 1) DSTORE(cur2, 2) DSTORE(cur3, 3)       \
    }                                                                         \
    if ((L) < 2) __syncthreads(); }

__global__ __launch_bounds__(512, 1) void cin_mfma(
    const float* __restrict__ x,
    const float* __restrict__ W0,
    const float* __restrict__ W1,
    const float* __restrict__ W2,
    const float* __restrict__ b0p,
    const float* __restrict__ b1p,
    const float* __restrict__ b2p,
    float* __restrict__ out)
{
    __shared__ __align__(16) unsigned short hfrag[8 * 64 * 8];  // [gblk][sl][j], 8 KB
    __shared__ float xf32[NF * 64];                             // [f][sl] fp32

    const int tid  = threadIdx.x;
    const int lane = tid & 63;
    const int w    = tid >> 6;      // wave 0..7 = n-tile
    const int q    = lane >> 4;     // quad 0..3
    const int c    = lane & 15;
    const int nc   = w * 16 + c;    // this lane's output channel
    const int bb   = blockIdx.x * 4;
    const int lane_off = q * 1024 + nc;   // q*8 rows * 128 + col

    // zero hfrag (covers layer-0 A-side padding g in [39,64))
    {
        f32x4 zz = {0.f, 0.f, 0.f, 0.f};
        ((f32x4*)hfrag)[tid] = zz;   // 512*16B = 8 KB exactly
    }
    __syncthreads();

    // stage x (contiguous 2496 floats for this block's 4 b's)
    for (int i = tid; i < 4 * NF * 16; i += 512) {
        const float v = x[bb * (NF * 16) + i];
        const int lb = i / (NF * 16);
        const int r  = i - lb * (NF * 16);
        const int f  = r >> 4;
        const int d  = r & 15;
        const int sl = lb * 16 + d;
        xf32[f * 64 + sl] = v;
        hfrag[((f >> 3) * 64 + sl) * 8 + (f & 7)] = f2bf_rne(v);
    }
    const float biasv0 = b0p[nc];
    const float biasv1 = b1p[nc];
    const float biasv2 = b2p[nc];

    // preload tiles (0,0) and (0,1) into the two named fp32 pairs
    f32x8 Fa, Fb, Sa, Sb;
    LOADW(Fa, Fb, 0, 0);
    LOADW(Sa, Sb, 0, 1);

    __syncthreads();   // x, hfrag ready

    // layers; buffer roles alternate because 39 is odd
    LAYERBODY(0, Fa, Fb, Sa, Sb)
    LAYERBODY(1, Sa, Sb, Fa, Fb)
    LAYERBODY(2, Fa, Fb, Sa, Sb)
}

extern "C" void kernel_launch(void* const* d_in, const int* in_sizes, int n_in,
                              void* d_out, int out_size, void* d_ws, size_t ws_size,
                              hipStream_t stream) {
    const float* x  = (const float*)d_in[0];
    const float* W0 = (const float*)d_in[1];
    const float* W1 = (const float*)d_in[2];
    const float* W2 = (const float*)d_in[3];
    const float* b0 = (const float*)d_in[4];
    const float* b1 = (const float*)d_in[5];
    const float* b2 = (const float*)d_in[6];
    float* out = (float*)d_out;

    cin_mfma<<<256, 512, 0, stream>>>(x, W0, W1, W2, b0, b1, b2, out);
}

// Round 11
// 118.138 us; speedup vs baseline: 7.8973x; 1.0176x over previous
//
#include <hip/hip_runtime.h>

// CIN fused 3-layer, bf16 MFMA, plain SINGLE kernel, fp32 W streaming (R11).
// cur[sl,n] = sum_f x_f[sl] * S_f[sl,n],  S_f = sum_g h_g[sl] * W[f*64+g, n].
// R10 finding: all blocks in tile lockstep -> per-XCD HBM miss storm every
// tile (~900cyc exposed), latency-bound at 1414 cyc/tile. R11:
//  - per-block rotated f-order (off = (blockIdx>>3)%39; sum over f is
//    order-independent): misses spread, W stays L2-resident after warmup.
//  - depth-3 prefetch (39%3==0 -> three named fp32 pairs keep phase across
//    layers, no role swap, no indexable arrays). Regs ~100 < 128 cap.
// No d_ws (ws-poison costs ~10-20us residual), no coop (+80us), no 2nd kernel.

#define NF     39
#define LCH    128
#define NLAYER 3

typedef __bf16        bf16x8 __attribute__((ext_vector_type(8)));
typedef unsigned int  uint4v __attribute__((ext_vector_type(4)));
typedef float         f32x4  __attribute__((ext_vector_type(4)));
typedef float         f32x8  __attribute__((ext_vector_type(8)));

__device__ __forceinline__ unsigned short f2bf_rne(float f) {
    unsigned u = __float_as_uint(f);
    u += 0x7fffu + ((u >> 16) & 1u);
    return (unsigned short)(u >> 16);
}

// pack 8 fp32 -> bf16x8 by truncation (4x v_perm; validated R7/R8/R10)
#define PACKBF(SRC) __builtin_bit_cast(bf16x8, (uint4v){                                             \
    __builtin_amdgcn_perm(__float_as_uint((SRC)[1]), __float_as_uint((SRC)[0]), 0x07060302u),        \
    __builtin_amdgcn_perm(__float_as_uint((SRC)[3]), __float_as_uint((SRC)[2]), 0x07060302u),        \
    __builtin_amdgcn_perm(__float_as_uint((SRC)[5]), __float_as_uint((SRC)[4]), 0x07060302u),        \
    __builtin_amdgcn_perm(__float_as_uint((SRC)[7]), __float_as_uint((SRC)[6]), 0x07060302u)})

// fp32 B-frag loads for consumption position POS_ (in [0, NF+2]) of layer PL_.
// Normalize one layer crossing, then apply the per-block rotation:
//   f = ((POS_ mod NF) + off) mod NF.
// Lane (q,c) of wave w needs W[k = ks*32 + q*8 + j][nc], j=0..7.
// Layer-0 rows are (f*39+g)*128, g<39: ks=0 fully valid; ks=1 only q==0,j<=6
// (f=38,q=0 max addr = exactly W0's last element).
#define LOADW(DA, DB, PL_, POS_)                                               \
  do { int _pl = (PL_), _pp = (POS_);                                          \
    if (_pp >= NF) { _pp -= NF; ++_pl; }                                       \
    if (_pl < NLAYER) {                                                        \
      int _pf = _pp + off; if (_pf >= NF) _pf -= NF;                           \
      const float* _base = (_pl == 0) ? (W0 + _pf * 4992)                      \
                         : (_pl == 1) ? (W1 + _pf * 8192)                      \
                                      : (W2 + _pf * 8192);                     \
      const float* _p0 = _base + lane_off;                                     \
      DA[0] = _p0[0];   DA[1] = _p0[128]; DA[2] = _p0[256]; DA[3] = _p0[384];  \
      DA[4] = _p0[512]; DA[5] = _p0[640]; DA[6] = _p0[768]; DA[7] = _p0[896];  \
      if (_pl == 0) {                                                          \
        if (q == 0) {                                                          \
          const float* _p1 = _base + 4096 + nc;                                \
          DB[0] = _p1[0];   DB[1] = _p1[128]; DB[2] = _p1[256];                \
          DB[3] = _p1[384]; DB[4] = _p1[512]; DB[5] = _p1[640];                \
          DB[6] = _p1[768]; DB[7] = 0.f;                                       \
        } else { DB = (f32x8){0,0,0,0,0,0,0,0}; }                              \
      } else {                                                                 \
        const float* _p1 = _p0 + 4096;                                         \
        DB[0] = _p1[0];   DB[1] = _p1[128]; DB[2] = _p1[256]; DB[3] = _p1[384];\
        DB[4] = _p1[512]; DB[5] = _p1[640]; DB[6] = _p1[768]; DB[7] = _p1[896];\
      }                                                                        \
    }                                                                          \
  } while (0)

__device__ __forceinline__ void mfma_step(
    const bf16x8 a00, const bf16x8 a01, const bf16x8 a02, const bf16x8 a03,
    const bf16x8 a10, const bf16x8 a11, const bf16x8 a12, const bf16x8 a13,
    const f32x8& ra, const f32x8& rb,
    f32x4& cur0, f32x4& cur1, f32x4& cur2, f32x4& cur3,
    const float* xrow, int q)
{
    const bf16x8 B0 = PACKBF(ra);
    const bf16x8 B1 = PACKBF(rb);
    const f32x4 z = {0.f, 0.f, 0.f, 0.f};
    f32x4 s0 = __builtin_amdgcn_mfma_f32_16x16x32_bf16(a00, B0, z, 0, 0, 0);
    f32x4 s1 = __builtin_amdgcn_mfma_f32_16x16x32_bf16(a01, B0, z, 0, 0, 0);
    f32x4 s2 = __builtin_amdgcn_mfma_f32_16x16x32_bf16(a02, B0, z, 0, 0, 0);
    f32x4 s3 = __builtin_amdgcn_mfma_f32_16x16x32_bf16(a03, B0, z, 0, 0, 0);
    s0 = __builtin_amdgcn_mfma_f32_16x16x32_bf16(a10, B1, s0, 0, 0, 0);
    s1 = __builtin_amdgcn_mfma_f32_16x16x32_bf16(a11, B1, s1, 0, 0, 0);
    s2 = __builtin_amdgcn_mfma_f32_16x16x32_bf16(a12, B1, s2, 0, 0, 0);
    s3 = __builtin_amdgcn_mfma_f32_16x16x32_bf16(a13, B1, s3, 0, 0, 0);
    const f32x4 xr0 = *(const f32x4*)&xrow[ 0 + q * 4];
    const f32x4 xr1 = *(const f32x4*)&xrow[16 + q * 4];
    const f32x4 xr2 = *(const f32x4*)&xrow[32 + q * 4];
    const f32x4 xr3 = *(const f32x4*)&xrow[48 + q * 4];
    #pragma unroll
    for (int r = 0; r < 4; ++r) {
        cur0[r] = fmaf(xr0[r], s0[r], cur0[r]);
        cur1[r] = fmaf(xr1[r], s1[r], cur1[r]);
        cur2[r] = fmaf(xr2[r], s2[r], cur2[r]);
        cur3[r] = fmaf(xr3[r], s3[r], cur3[r]);
    }
}

#define HSTORE(CUR, MT)                                                       \
    { hfrag[((nc >> 3) * 64 + (MT) * 16 + q * 4 + 0) * 8 + (nc & 7)] =        \
          f2bf_rne(fmaxf(CUR[0] + bias, 0.f));                                \
      hfrag[((nc >> 3) * 64 + (MT) * 16 + q * 4 + 1) * 8 + (nc & 7)] =        \
          f2bf_rne(fmaxf(CUR[1] + bias, 0.f));                                \
      hfrag[((nc >> 3) * 64 + (MT) * 16 + q * 4 + 2) * 8 + (nc & 7)] =        \
          f2bf_rne(fmaxf(CUR[2] + bias, 0.f));                                \
      hfrag[((nc >> 3) * 64 + (MT) * 16 + q * 4 + 3) * 8 + (nc & 7)] =        \
          f2bf_rne(fmaxf(CUR[3] + bias, 0.f)); }

#define DSTORE(CUR, MT)                                                       \
    { float sacc = fmaxf(CUR[0] + bias, 0.f) + fmaxf(CUR[1] + bias, 0.f)      \
                 + fmaxf(CUR[2] + bias, 0.f) + fmaxf(CUR[3] + bias, 0.f);     \
      sacc += __shfl_xor(sacc, 16, 64);                                       \
      sacc += __shfl_xor(sacc, 32, 64);                                       \
      if (lane < 16) out[(bb + (MT)) * 256 + outcol] = sacc; }

__global__ __launch_bounds__(512, 1) void cin_mfma(
    const float* __restrict__ x,
    const float* __restrict__ W0,
    const float* __restrict__ W1,
    const float* __restrict__ W2,
    const float* __restrict__ b0p,
    const float* __restrict__ b1p,
    const float* __restrict__ b2p,
    float* __restrict__ out)
{
    __shared__ __align__(16) unsigned short hfrag[8 * 64 * 8];  // [gblk][sl][j], 8 KB
    __shared__ float xf32[NF * 64];                             // [f][sl] fp32

    const int tid  = threadIdx.x;
    const int lane = tid & 63;
    const int w    = tid >> 6;      // wave 0..7 = n-tile
    const int q    = lane >> 4;     // quad 0..3
    const int c    = lane & 15;
    const int nc   = w * 16 + c;    // this lane's output channel
    const int bb   = blockIdx.x * 4;
    const int lane_off = q * 1024 + nc;            // q*8 rows * 128 + col
    const int off  = (blockIdx.x >> 3) % NF;       // per-XCD tile-order rotation

    // zero hfrag (covers layer-0 A-side padding g in [39,64))
    {
        f32x4 zz = {0.f, 0.f, 0.f, 0.f};
        ((f32x4*)hfrag)[tid] = zz;   // 512*16B = 8 KB exactly
    }
    __syncthreads();

    // stage x (contiguous 2496 floats for this block's 4 b's)
    for (int i = tid; i < 4 * NF * 16; i += 512) {
        const float v = x[bb * (NF * 16) + i];
        const int lb = i / (NF * 16);
        const int r  = i - lb * (NF * 16);
        const int f  = r >> 4;
        const int d  = r & 15;
        const int sl = lb * 16 + d;
        xf32[f * 64 + sl] = v;
        hfrag[((f >> 3) * 64 + sl) * 8 + (f & 7)] = f2bf_rne(v);
    }
    const float biasv0 = b0p[nc];
    const float biasv1 = b1p[nc];
    const float biasv2 = b2p[nc];

    // preload positions 0,1,2 of layer 0 into the three named fp32 pairs
    f32x8 P0a, P0b, P1a, P1b, P2a, P2b;
    LOADW(P0a, P0b, 0, 0);
    LOADW(P1a, P1b, 0, 1);
    LOADW(P2a, P2b, 0, 2);

    __syncthreads();   // x, hfrag ready

    #pragma unroll 1
    for (int l = 0; l < NLAYER; ++l) {
        // hoist A-frags (h) for this layer
        const bf16x8 a00 = *(const bf16x8*)&hfrag[((0 + q) * 64 +  0 + c) * 8];
        const bf16x8 a01 = *(const bf16x8*)&hfrag[((0 + q) * 64 + 16 + c) * 8];
        const bf16x8 a02 = *(const bf16x8*)&hfrag[((0 + q) * 64 + 32 + c) * 8];
        const bf16x8 a03 = *(const bf16x8*)&hfrag[((0 + q) * 64 + 48 + c) * 8];
        const bf16x8 a10 = *(const bf16x8*)&hfrag[((4 + q) * 64 +  0 + c) * 8];
        const bf16x8 a11 = *(const bf16x8*)&hfrag[((4 + q) * 64 + 16 + c) * 8];
        const bf16x8 a12 = *(const bf16x8*)&hfrag[((4 + q) * 64 + 32 + c) * 8];
        const bf16x8 a13 = *(const bf16x8*)&hfrag[((4 + q) * 64 + 48 + c) * 8];

        f32x4 cur0 = {0,0,0,0}, cur1 = {0,0,0,0};
        f32x4 cur2 = {0,0,0,0}, cur3 = {0,0,0,0};

        // 39 = 13 x 3 steps; depth-3 keeps buffer phase across layers
        #pragma unroll 1
        for (int fi = 0; fi < NF; fi += 3) {
            int f0 = fi + 0 + off; if (f0 >= NF) f0 -= NF;
            int f1 = fi + 1 + off; if (f1 >= NF) f1 -= NF;
            int f2 = fi + 2 + off; if (f2 >= NF) f2 -= NF;

            mfma_step(a00,a01,a02,a03,a10,a11,a12,a13, P0a, P0b,
                      cur0,cur1,cur2,cur3, &xf32[f0 * 64], q);
            LOADW(P0a, P0b, l, fi + 3);
            mfma_step(a00,a01,a02,a03,a10,a11,a12,a13, P1a, P1b,
                      cur0,cur1,cur2,cur3, &xf32[f1 * 64], q);
            LOADW(P1a, P1b, l, fi + 4);
            mfma_step(a00,a01,a02,a03,a10,a11,a12,a13, P2a, P2b,
                      cur0,cur1,cur2,cur3, &xf32[f2 * 64], q);
            LOADW(P2a, P2b, l, fi + 5);
        }

        // ---------------- epilogue for layer l ----------------
        const float bias = (l == 0) ? biasv0 : (l == 1) ? biasv1 : biasv2;
        if (l < 2 && w < 4) {
            HSTORE(cur0, 0) HSTORE(cur1, 1) HSTORE(cur2, 2) HSTORE(cur3, 3)
        } else {
            const int outcol = (l == 0) ? nc - 64 : (l == 1) ? nc : 128 + nc;
            DSTORE(cur0, 0) DSTORE(cur1, 1) DSTORE(cur2, 2) DSTORE(cur3, 3)
        }
        if (l < 2) __syncthreads();   // h writes visible before next A-hoist
    }
}

extern "C" void kernel_launch(void* const* d_in, const int* in_sizes, int n_in,
                              void* d_out, int out_size, void* d_ws, size_t ws_size,
                              hipStream_t stream) {
    const float* x  = (const float*)d_in[0];
    const float* W0 = (const float*)d_in[1];
    const float* W1 = (const float*)d_in[2];
    const float* W2 = (const float*)d_in[3];
    const float* b0 = (const float*)d_in[4];
    const float* b1 = (const float*)d_in[5];
    const float* b2 = (const float*)d_in[6];
    float* out = (float*)d_out;

    cin_mfma<<<256, 512, 0, stream>>>(x, W0, W1, W2, b0, b1, b2, out);
}